// Round 1
// baseline (252.084 us; speedup 1.0000x reference)
//
#include <hip/hip_runtime.h>
#include <hip/hip_bf16.h>
#include <hip/hip_fp16.h>
#include <stdint.h>

typedef short s8v __attribute__((ext_vector_type(8)));
typedef float f4v __attribute__((ext_vector_type(4)));

// ---- workspace byte offsets ----
#define FMT_OFF   0          // bf16 fmT [120*120][64]            : 1,843,200 B
#define GF_OFF    1843200    // float gf[64]
#define G_OFF     1843456    // float g[16]
#define W1P_OFF   1843712    // bf16 permuted+swizzled W1 (a,b,c) : 2,932,736 B
#define W2T_OFF   4776448    // bf16 swizzled W2t [3][32][128]    : 24,576 B
#define WTAB_OFF  4801024    // int2 {offs, half2(wx,wy)} x 1,466,368 : 11,730,944 B
// total needed: 16,531,968 B

__device__ __forceinline__ unsigned short f2bf(float f) {
  unsigned int u = __float_as_uint(f);
  u += 0x7fffu + ((u >> 16) & 1u);
  return (unsigned short)(u >> 16);
}
__device__ __forceinline__ float bflo(unsigned int u) { return __uint_as_float(u << 16); }
__device__ __forceinline__ float bfhi(unsigned int u) { return __uint_as_float(u & 0xffff0000u); }

// ---- channel means of fm -> gf ----
__global__ void k_mean(const float* __restrict__ fm, float* __restrict__ gf) {
  __shared__ float red[4];
  int c = blockIdx.x, t = threadIdx.x;
  const float* p = fm + c * 14400;
  float s = 0.f;
  for (int i = t; i < 14400; i += 256) s += p[i];
  #pragma unroll
  for (int off = 32; off > 0; off >>= 1) s += __shfl_down(s, off);
  if ((t & 63) == 0) red[t >> 6] = s;
  __syncthreads();
  if (t == 0) gf[c] = (red[0] + red[1] + red[2] + red[3]) * (1.0f / 14400.0f);
}

// ---- g = gf @ Wg.T + bg ----
__global__ void k_g(const float* __restrict__ gf, const float* __restrict__ Wg,
                    const float* __restrict__ bg, float* __restrict__ g) {
  int d = threadIdx.x;
  if (d < 16) {
    float s = bg[d];
    for (int c = 0; c < 64; ++c) s += gf[c] * Wg[d * 64 + c];
    g[d] = s;
  }
}

// ---- fm [C][H][W] f32 -> fmT [H*W][C] bf16 ----
__global__ void k_transpose(const float* __restrict__ fm, unsigned short* __restrict__ fmT) {
  int t = blockIdx.x * 256 + threadIdx.x;   // t < 921600
  int pix = t >> 6, c = t & 63;
  fmT[t] = f2bf(fm[c * 14400 + pix]);
}

// ---- W1 -> per-point 16KB chunks, k' = p*64+c, bf16, XOR-swizzled rows ----
__global__ void k_w1perm(const float* __restrict__ W1a, const float* __restrict__ W1b,
                         const float* __restrict__ W1c, unsigned short* __restrict__ w1p) {
  int t = blockIdx.x * 256 + threadIdx.x;   // t < 1,466,368
  const float* W1; int rr, base, tl;
  if (t < 73728)       { W1 = W1a; rr = 9;   base = 0;      tl = t; }
  else if (t < 475136) { W1 = W1b; rr = 49;  base = 147456; tl = t - 73728; }
  else                 { W1 = W1c; rr = 121; base = 950272; tl = t - 475136; }
  int p = tl >> 13, e = tl & 8191, j = e >> 6, c = e & 63;
  float v = W1[j * (rr * 64) + c * rr + p];
  int byteoff = base + p * 16384 + (((j << 7) | (c << 1)) ^ ((j & 7) << 4));
  w1p[byteoff >> 1] = f2bf(v);
}

// ---- W2 -> [32 n][128 k] bf16 tiles (n>=od zero), XOR-swizzled ----
__global__ void k_w2prep(const float* __restrict__ W2a, const float* __restrict__ W2b,
                         const float* __restrict__ W2c, unsigned short* __restrict__ w2t) {
  int t = blockIdx.x * 256 + threadIdx.x;   // t < 12288
  int head = t >> 12, e = t & 4095, n = e >> 7, k = e & 127;
  const float* W2 = head == 0 ? W2a : (head == 1 ? W2b : W2c);
  int od = head == 0 ? 22 : 21;
  float v = (n < od) ? W2[n * 128 + k] : 0.0f;
  int byteoff = head * 8192 + (((n << 8) | (k << 1)) ^ ((n & 7) << 4));
  w2t[byteoff >> 1] = f2bf(v);
}

// ---- per (head, point, box): corner offset + bilinear weights ----
__global__ void k_wtab(const float* __restrict__ boxes, int2* __restrict__ wtab) {
  int t = blockIdx.x * 256 + threadIdx.x;   // t < 1,466,368
  int r, tl;
  if (t < 73728)       { r = 3;  tl = t; }
  else if (t < 475136) { r = 7;  tl = t - 73728; }
  else                 { r = 11; tl = t - 475136; }
  int p = tl >> 13, box = tl & 8191;
  int py = p / r, px = p - py * r;
  float4 bx = ((const float4*)boxes)[box];
  float inv = 1.0f / (float)(r - 1);
  float txv = (float)px * inv, tyv = (float)py * inv;
  float x1 = bx.x * (1.0f / 480.0f) - 1.0f;
  float y1 = bx.y * (1.0f / 480.0f) - 1.0f;
  float x2 = bx.z * (1.0f / 480.0f) - 1.0f;
  float y2 = bx.w * (1.0f / 480.0f) - 1.0f;
  float gx = txv * (x2 - x1) + x1;
  float gy = tyv * (y2 - y1) + y1;
  float ix = (gx + 1.0f) * 0.5f * 119.0f;
  float iy = (gy + 1.0f) * 0.5f * 119.0f;
  float x0f = floorf(ix), y0f = floorf(iy);
  float wxv = ix - x0f, wyv = iy - y0f;
  int x0 = (int)x0f, y0 = (int)y0f;
  x0 = min(max(x0, 0), 118);
  y0 = min(max(y0, 0), 118);
  __half2 h2 = __floats2half2_rn(wxv, wyv);
  union { __half2 h; int i; } u; u.h = h2;
  wtab[t] = make_int2((y0 * 120 + x0) << 6, u.i);
}

// ---- fused ROI-sample + 2-layer MLP, one 32-box tile per block ----
__global__ __launch_bounds__(512, 4) void k_main(
    const unsigned short* __restrict__ fmT,
    const int2* __restrict__ wtab,
    const unsigned short* __restrict__ w1p,
    const unsigned short* __restrict__ w2t,
    const float* __restrict__ gvec,
    const float* __restrict__ b1a, const float* __restrict__ b1b, const float* __restrict__ b1c,
    const float* __restrict__ b2a, const float* __restrict__ b2b, const float* __restrict__ b2c,
    const float* __restrict__ scale_w,
    float* __restrict__ out)
{
  __shared__ __align__(16) char lds[20480];   // A: [0,4K) B: [4K,20K); epilogue h:[0,8K) W2t:[8K,16K)
  int bi = blockIdx.x;
  int head, tile;
  if (bi < 256)      { head = 2; tile = bi; }        // head c first (most work)
  else if (bi < 512) { head = 1; tile = bi - 256; }
  else               { head = 0; tile = bi - 512; }

  int npts, colbase, odh, w1base, tabbase;
  const float *b1h, *b2h;
  if (head == 0)      { npts = 9;   colbase = 0;  odh = 22; w1base = 0;      tabbase = 0;      b1h = b1a; b2h = b2a; }
  else if (head == 1) { npts = 49;  colbase = 22; odh = 21; w1base = 147456; tabbase = 73728;  b1h = b1b; b2h = b2b; }
  else                { npts = 121; colbase = 43; odh = 5;  w1base = 950272; tabbase = 475136; b1h = b1c; b2h = b2c; }

  int tid = threadIdx.x;
  int w = tid >> 6, lane = tid & 63;
  int half = lane >> 5, l1 = lane & 31;
  int l15 = lane & 15, kgrp = lane >> 4;
  int boxbase = tile * 32;
  int wm = w & 1, wc = w >> 1;   // m-frag (16 boxes), col-group (32 of 128 hidden)

  f4v acc[2];
  acc[0] = (f4v){0.f, 0.f, 0.f, 0.f};
  acc[1] = (f4v){0.f, 0.f, 0.f, 0.f};

  const char* w1g = (const char*)w1p + w1base;

  for (int p = 0; p < npts; ++p) {
    // B-tile (one K=64 chunk of permuted W1, already swizzled): regs first (hide latency)
    const uint4* bsrc = (const uint4*)(w1g + p * 16384 + tid * 32);
    uint4 br0 = bsrc[0];
    uint4 br1 = bsrc[1];

    // A-tile: bilinear sample 64 channels for grid point p; lanes = channel pairs,
    // halves of wave = 2 boxes; each wave covers 4 boxes.
    int tb = tabbase + p * 8192 + boxbase;
    #pragma unroll
    for (int bp = 0; bp < 2; ++bp) {
      int bl = w * 4 + bp * 2 + half;
      int2 tv = wtab[tb + bl];
      union { int i; __half2 h; } uu; uu.i = tv.y;
      float wxv = __low2float(uu.h), wyv = __high2float(uu.h);
      const char* src = (const char*)fmT + tv.x * 2 + l1 * 4;
      unsigned int c00 = *(const unsigned int*)(src);
      unsigned int c01 = *(const unsigned int*)(src + 128);     // x0+1
      unsigned int c10 = *(const unsigned int*)(src + 15360);   // y0+1
      unsigned int c11 = *(const unsigned int*)(src + 15488);
      float a00 = bflo(c00), q00 = bfhi(c00);
      float a01 = bflo(c01), q01 = bfhi(c01);
      float a10 = bflo(c10), q10 = bfhi(c10);
      float a11 = bflo(c11), q11 = bfhi(c11);
      float t0 = a00 + wxv * (a01 - a00);
      float u0 = a10 + wxv * (a11 - a10);
      float v0 = t0 + wyv * (u0 - t0);
      float t1 = q00 + wxv * (q01 - q00);
      float u1 = q10 + wxv * (q11 - q10);
      float v1 = t1 + wyv * (u1 - t1);
      unsigned int pk = (unsigned int)f2bf(v0) | ((unsigned int)f2bf(v1) << 16);
      int ab = ((bl << 7) | (l1 << 2)) ^ ((bl & 7) << 4);
      *(unsigned int*)(lds + ab) = pk;
    }
    {
      char* bd = lds + 4096 + tid * 32;
      *(uint4*)(bd) = br0;
      *(uint4*)(bd + 16) = br1;
    }
    __syncthreads();

    // 16x16x32 bf16 MFMA: wave tile 16 boxes x 32 hidden, K=64 chunk = 2 k-steps
    s8v af0, af1;
    {
      int rrow = wm * 16 + l15;
      int base0 = rrow * 128 + kgrp * 16;
      af0 = *(const s8v*)(lds + ((base0)      ^ ((rrow & 7) << 4)));
      af1 = *(const s8v*)(lds + ((base0 + 64) ^ ((rrow & 7) << 4)));
    }
    #pragma unroll
    for (int nb = 0; nb < 2; ++nb) {
      int cn = wc * 32 + nb * 16 + l15;
      int base0 = cn * 128 + kgrp * 16;
      s8v bf0 = *(const s8v*)(lds + 4096 + ((base0)      ^ ((cn & 7) << 4)));
      s8v bf1 = *(const s8v*)(lds + 4096 + ((base0 + 64) ^ ((cn & 7) << 4)));
      acc[nb] = __builtin_amdgcn_mfma_f32_16x16x32_bf16(af0, bf0, acc[nb], 0, 0, 0);
      acc[nb] = __builtin_amdgcn_mfma_f32_16x16x32_bf16(af1, bf1, acc[nb], 0, 0, 0);
    }
    __syncthreads();
  }

  // ---- layer 2 (bf16 MFMA, K=128, N=32 padded) ----
  {
    const uint4* wsrc = (const uint4*)((const char*)w2t + head * 8192 + tid * 16);
    uint4 wv = *wsrc;
    *(uint4*)(lds + 8192 + tid * 16) = wv;
  }
  #pragma unroll
  for (int nb = 0; nb < 2; ++nb) {
    int cn = wc * 32 + nb * 16 + l15;
    float b1v = b1h[cn];
    #pragma unroll
    for (int e = 0; e < 4; ++e) {
      int rrow = wm * 16 + kgrp * 4 + e;
      float hv = fmaxf(acc[nb][e] + b1v, 0.0f);
      int hb = (rrow * 256 + cn * 2) ^ ((rrow & 7) << 4);
      *(unsigned short*)(lds + hb) = f2bf(hv);
    }
  }
  __syncthreads();

  if (w < 4) {
    int m = w & 1, nb2 = w >> 1;
    f4v a2 = (f4v){0.f, 0.f, 0.f, 0.f};
    int mrow = m * 16 + l15;
    int d = nb2 * 16 + l15;
    #pragma unroll
    for (int ks = 0; ks < 4; ++ks) {
      int ab = (mrow * 256 + ks * 64 + kgrp * 16) ^ ((mrow & 7) << 4);
      s8v ha = *(const s8v*)(lds + ab);
      int bb = 8192 + ((d * 256 + ks * 64 + kgrp * 16) ^ ((d & 7) << 4));
      s8v wb = *(const s8v*)(lds + bb);
      a2 = __builtin_amdgcn_mfma_f32_16x16x32_bf16(ha, wb, a2, 0, 0, 0);
    }
    if (d < odh) {
      float sc = scale_w[head];
      float b2v = b2h[d];
      #pragma unroll
      for (int e = 0; e < 4; ++e) {
        int box = boxbase + m * 16 + kgrp * 4 + e;
        out[box * 64 + colbase + d] = fmaxf(a2[e] + b2v, 0.0f) * sc;
      }
    }
  }
  if (head == 0) {   // head-a blocks also broadcast g into cols 48..63
    int box = boxbase + (tid >> 4);
    out[box * 64 + 48 + (tid & 15)] = gvec[tid & 15];
  }
}

extern "C" void kernel_launch(void* const* d_in, const int* in_sizes, int n_in,
                              void* d_out, int out_size, void* d_ws, size_t ws_size,
                              hipStream_t stream) {
  const float* fm      = (const float*)d_in[0];
  const float* boxes   = (const float*)d_in[1];
  const float* W1a     = (const float*)d_in[2];
  const float* b1a     = (const float*)d_in[3];
  const float* W2a     = (const float*)d_in[4];
  const float* b2a     = (const float*)d_in[5];
  const float* W1b     = (const float*)d_in[6];
  const float* b1b     = (const float*)d_in[7];
  const float* W2b     = (const float*)d_in[8];
  const float* b2b     = (const float*)d_in[9];
  const float* W1c     = (const float*)d_in[10];
  const float* b1c     = (const float*)d_in[11];
  const float* W2c     = (const float*)d_in[12];
  const float* b2c     = (const float*)d_in[13];
  const float* scale_w = (const float*)d_in[14];
  const float* Wg      = (const float*)d_in[15];
  const float* bg      = (const float*)d_in[16];

  char* ws = (char*)d_ws;
  unsigned short* fmT = (unsigned short*)(ws + FMT_OFF);
  float* gf           = (float*)(ws + GF_OFF);
  float* g            = (float*)(ws + G_OFF);
  unsigned short* w1p = (unsigned short*)(ws + W1P_OFF);
  unsigned short* w2t = (unsigned short*)(ws + W2T_OFF);
  int2* wtab          = (int2*)(ws + WTAB_OFF);
  float* out          = (float*)d_out;

  k_mean<<<64, 256, 0, stream>>>(fm, gf);
  k_g<<<1, 64, 0, stream>>>(gf, Wg, bg, g);
  k_transpose<<<3600, 256, 0, stream>>>(fm, fmT);
  k_w1perm<<<5728, 256, 0, stream>>>(W1a, W1b, W1c, w1p);
  k_w2prep<<<48, 256, 0, stream>>>(W2a, W2b, W2c, w2t);
  k_wtab<<<5728, 256, 0, stream>>>(boxes, wtab);
  k_main<<<768, 512, 0, stream>>>(fmT, wtab, w1p, w2t, g,
                                  b1a, b1b, b1c, b2a, b2b, b2c, scale_w, out);
}

// Round 2
// 229.136 us; speedup vs baseline: 1.1001x; 1.1001x over previous
//
#include <hip/hip_runtime.h>
#include <hip/hip_bf16.h>
#include <hip/hip_fp16.h>
#include <stdint.h>

typedef float f4v __attribute__((ext_vector_type(4)));
typedef _Float16 h8v __attribute__((ext_vector_type(8)));

// ---- workspace byte offsets ----
#define FMT_OFF   0          // f16 fmT [120*120][64]             : 1,843,200 B
#define GF_OFF    1843200    // float gf[64]
#define G_OFF     1843456    // float g[16]
#define W1P_OFF   1843712    // f16 permuted+swizzled W1 (a,b,c)  : 2,932,736 B
#define W2T_OFF   4776448    // f16 w2t [3][32][128] linear       : 24,576 B
#define WTAB_OFF  4801024    // int2 {byteoff, half2(wx,wy)} x 1,466,368 : 11,730,944 B

#define GLD(gp, lp) __builtin_amdgcn_global_load_lds( \
    (const __attribute__((address_space(1))) uint32_t*)(uintptr_t)(gp), \
    (__attribute__((address_space(3))) uint32_t*)(uintptr_t)(lp), 16, 0, 0)

__device__ __forceinline__ unsigned short f2hbits(float f) {
  __half h = __float2half_rn(f);
  union { __half h; unsigned short s; } u; u.h = h; return u.s;
}
__device__ __forceinline__ __half2 uh(unsigned int x) {
  union { unsigned int u; __half2 h; } v; v.u = x; return v.h;
}
__device__ __forceinline__ unsigned int hu(__half2 h) {
  union { __half2 h; unsigned int u; } v; v.h = h; return v.u;
}

// ---- channel means of fm -> gf ----
__global__ void k_mean(const float* __restrict__ fm, float* __restrict__ gf) {
  __shared__ float red[4];
  int c = blockIdx.x, t = threadIdx.x;
  const float* p = fm + c * 14400;
  float s = 0.f;
  for (int i = t; i < 14400; i += 256) s += p[i];
  #pragma unroll
  for (int off = 32; off > 0; off >>= 1) s += __shfl_down(s, off);
  if ((t & 63) == 0) red[t >> 6] = s;
  __syncthreads();
  if (t == 0) gf[c] = (red[0] + red[1] + red[2] + red[3]) * (1.0f / 14400.0f);
}

// ---- g = gf @ Wg.T + bg ----
__global__ void k_g(const float* __restrict__ gf, const float* __restrict__ Wg,
                    const float* __restrict__ bg, float* __restrict__ g) {
  int d = threadIdx.x;
  if (d < 16) {
    float s = bg[d];
    for (int c = 0; c < 64; ++c) s += gf[c] * Wg[d * 64 + c];
    g[d] = s;
  }
}

// ---- fm [64][120][120] f32 -> fmT [pix][64] f16, LDS-tiled transpose ----
__global__ void k_transpose(const float* __restrict__ fm, unsigned int* __restrict__ fmT32) {
  __shared__ float tile[64][65];
  int pixbase = blockIdx.x * 64, t = threadIdx.x;
  #pragma unroll
  for (int k = 0; k < 16; ++k) {
    int c = k * 4 + (t >> 6);
    tile[c][t & 63] = fm[c * 14400 + pixbase + (t & 63)];
  }
  __syncthreads();
  #pragma unroll
  for (int k = 0; k < 8; ++k) {
    int p = k * 8 + (t >> 5), i = t & 31;
    __half2 h = __floats2half2_rn(tile[2 * i][p], tile[2 * i + 1][p]);
    fmT32[(pixbase + p) * 32 + i] = hu(h);
  }
}

// ---- W1 rows -> per-point 16KB chunks (f16, XOR-swizzled), coalesced both sides ----
__global__ void k_w1perm(const float* __restrict__ W1a, const float* __restrict__ W1b,
                         const float* __restrict__ W1c, unsigned short* __restrict__ w1p) {
  __shared__ float row[7744];
  int bi = blockIdx.x, t = threadIdx.x;
  int head = bi >> 7, j = bi & 127;
  const float* W1; int rr, base;
  if (head == 0)      { W1 = W1a; rr = 9;   base = 0; }
  else if (head == 1) { W1 = W1b; rr = 49;  base = 147456; }
  else                { W1 = W1c; rr = 121; base = 950272; }
  int fin = rr * 64;
  for (int idx = t; idx < fin; idx += 256) row[idx] = W1[j * fin + idx];
  __syncthreads();
  int swz = (j & 7) << 4;
  for (int idx = t; idx < fin; idx += 256) {
    int c = idx & 63, p = idx >> 6;
    int byteoff = base + p * 16384 + ((j * 128 + c * 2) ^ swz);
    w1p[byteoff >> 1] = f2hbits(row[c * rr + p]);
  }
}

// ---- W2 -> [3][32 n][128 k] f16 linear (zero-padded) ----
__global__ void k_w2prep(const float* __restrict__ W2a, const float* __restrict__ W2b,
                         const float* __restrict__ W2c, unsigned short* __restrict__ w2t) {
  int t = blockIdx.x * 256 + threadIdx.x;   // t < 12288
  int head = t >> 12, e = t & 4095, n = e >> 7, k = e & 127;
  const float* W2 = head == 0 ? W2a : (head == 1 ? W2b : W2c);
  int od = head == 0 ? 22 : 21;
  float v = (n < od) ? W2[n * 128 + k] : 0.0f;
  w2t[t] = f2hbits(v);
}

// ---- per (head, point, box): corner byte-offset + half2(wx,wy) ----
template<int R>
__device__ __forceinline__ int2 wtab_entry(const float* __restrict__ boxes, int tl) {
  int p = tl >> 13, box = tl & 8191;
  int py = p / R, px = p - py * R;
  float4 bx = ((const float4*)boxes)[box];
  float inv = 1.0f / (float)(R - 1);
  float txv = (float)px * inv, tyv = (float)py * inv;
  float x1 = bx.x * (1.0f / 480.0f) - 1.0f;
  float y1 = bx.y * (1.0f / 480.0f) - 1.0f;
  float x2 = bx.z * (1.0f / 480.0f) - 1.0f;
  float y2 = bx.w * (1.0f / 480.0f) - 1.0f;
  float gx = txv * (x2 - x1) + x1;
  float gy = tyv * (y2 - y1) + y1;
  float ix = (gx + 1.0f) * 0.5f * 119.0f;
  float iy = (gy + 1.0f) * 0.5f * 119.0f;
  float x0f = floorf(ix), y0f = floorf(iy);
  float wxv = ix - x0f, wyv = iy - y0f;
  int x0 = min(max((int)x0f, 0), 118);
  int y0 = min(max((int)y0f, 0), 118);
  return make_int2((y0 * 120 + x0) * 128, (int)hu(__floats2half2_rn(wxv, wyv)));
}

__global__ void k_wtab(const float* __restrict__ boxes, int2* __restrict__ wtab) {
  int t = blockIdx.x * 256 + threadIdx.x;   // t < 1,466,368
  int2 e;
  if (t < 73728)       e = wtab_entry<3>(boxes, t);
  else if (t < 475136) e = wtab_entry<7>(boxes, t - 73728);
  else                 e = wtab_entry<11>(boxes, t - 475136);
  wtab[t] = e;
}

// ---- bilinear sample of 4 channels -> swizzled LDS write ----
__device__ __forceinline__ void sample4(const char* __restrict__ fmT, int2 tv,
                                        int sbox, int scg, char* lds, int q) {
  __half2 wh = uh((unsigned int)tv.y);
  __half2 wx2 = __half2half2(__low2half(wh));
  __half2 wy2 = __half2half2(__high2half(wh));
  const char* src = fmT + tv.x + scg * 8;
  uint2 r00 = *(const uint2*)(src);
  uint2 r01 = *(const uint2*)(src + 128);
  uint2 r10 = *(const uint2*)(src + 15360);
  uint2 r11 = *(const uint2*)(src + 15488);
  __half2 a0 = uh(r00.x), a1 = uh(r00.y);
  __half2 b0 = uh(r01.x), b1 = uh(r01.y);
  __half2 c0 = uh(r10.x), c1 = uh(r10.y);
  __half2 d0 = uh(r11.x), d1 = uh(r11.y);
  __half2 t0 = __hfma2(wx2, __hsub2(b0, a0), a0);
  __half2 u0 = __hfma2(wx2, __hsub2(d0, c0), c0);
  __half2 v0 = __hfma2(wy2, __hsub2(u0, t0), t0);
  __half2 t1 = __hfma2(wx2, __hsub2(b1, a1), a1);
  __half2 u1 = __hfma2(wx2, __hsub2(d1, c1), c1);
  __half2 v1 = __hfma2(wy2, __hsub2(u1, t1), t1);
  int ab = q * 4096 + ((sbox * 128 + scg * 8) ^ ((sbox & 7) << 4));
  *(uint2*)(lds + ab) = make_uint2(hu(v0), hu(v1));
}

// ---- fused ROI-sample + 2-layer MLP; 32-box tile, 2 points/iter, wave K-split ----
__global__ __launch_bounds__(512, 6) void k_main(
    const char* __restrict__ fmT,
    const int2* __restrict__ wtab,
    const char* __restrict__ w1p,
    const char* __restrict__ w2t,
    const float* __restrict__ gvec,
    const float* __restrict__ b1a, const float* __restrict__ b1b, const float* __restrict__ b1c,
    const float* __restrict__ b2a, const float* __restrict__ b2b, const float* __restrict__ b2c,
    const float* __restrict__ scale_w,
    float* __restrict__ out)
{
  __shared__ __align__(16) char lds[40960];  // A:[0,8K)x2pts  B:[8K,40K)x2pts
                                             // epilogue: xchg [0,16K), h16 [16K,24K)
  int bi = blockIdx.x;
  int head, tile;
  if (bi < 256)      { head = 2; tile = bi; }
  else if (bi < 512) { head = 1; tile = bi - 256; }
  else               { head = 0; tile = bi - 512; }

  int npts, colbase, odh, w1base, tabbase;
  const float *b1h, *b2h;
  if (head == 0)      { npts = 9;   colbase = 0;  odh = 22; w1base = 0;      tabbase = 0;      b1h = b1a; b2h = b2a; }
  else if (head == 1) { npts = 49;  colbase = 22; odh = 21; w1base = 147456; tabbase = 73728;  b1h = b1b; b2h = b2b; }
  else                { npts = 121; colbase = 43; odh = 5;  w1base = 950272; tabbase = 475136; b1h = b1c; b2h = b2c; }

  int tid = threadIdx.x;
  int w = tid >> 6, lane = tid & 63;
  int l15 = lane & 15, kgrp = lane >> 4;
  int kg = w >> 2, wc = w & 3;        // kg: K-split group; wc: 32-col group
  int sbox = tid >> 4, scg = tid & 15; // sampler: box 0..31, channel-group 0..15
  int boxbase = tile * 32;

  f4v acc[2][2];
  #pragma unroll
  for (int m = 0; m < 2; ++m)
    #pragma unroll
    for (int n = 0; n < 2; ++n) acc[m][n] = (f4v){0.f, 0.f, 0.f, 0.f};

  const char* w1g = w1p + w1base;
  int niter = (npts + 1) >> 1;
  int tbB = tabbase * 1 + boxbase + sbox;   // wtab element index base

  int2 tv0 = wtab[tbB];                        // p=0
  int2 tv1 = wtab[tbB + min(1, npts - 1) * 8192];

  for (int it = 0; it < niter; ++it) {
    int p0 = 2 * it, p1 = 2 * it + 1;
    bool has1 = (p1 < npts);

    // stage B tiles (pre-swizzled in global -> linear LDS copy)
    {
      int chunk = w * 2;
      const char* s0 = w1g + p0 * 16384 + chunk * 1024 + lane * 16;
      char* d0 = lds + 8192 + chunk * 1024;
      GLD(s0, d0);
      GLD(s0 + 1024, d0 + 1024);
      if (has1) {
        const char* s1 = w1g + p1 * 16384 + chunk * 1024 + lane * 16;
        char* d1 = lds + 24576 + chunk * 1024;
        GLD(s1, d1);
        GLD(s1 + 1024, d1 + 1024);
      }
    }

    // prefetch next iteration's wtab entries
    int pn0 = min(2 * it + 2, npts - 1);
    int pn1 = min(2 * it + 3, npts - 1);
    int2 ntv0 = wtab[tbB + pn0 * 8192];
    int2 ntv1 = wtab[tbB + pn1 * 8192];

    // A tiles: bilinear sample (packed f16)
    sample4(fmT, tv0, sbox, scg, lds, 0);
    if (has1) sample4(fmT, tv1, sbox, scg, lds, 1);
    __syncthreads();

    if (kg == 0 || has1) {
      const char* abase = lds + kg * 4096;
      const char* bbase = lds + 8192 + kg * 16384;
      #pragma unroll
      for (int ks = 0; ks < 2; ++ks) {
        h8v af[2], bf[2];
        #pragma unroll
        for (int m = 0; m < 2; ++m) {
          int rrow = m * 16 + l15;
          af[m] = *(const h8v*)(abase + ((rrow * 128 + ks * 64 + kgrp * 16) ^ ((rrow & 7) << 4)));
        }
        #pragma unroll
        for (int n = 0; n < 2; ++n) {
          int nrow = wc * 32 + n * 16 + l15;
          bf[n] = *(const h8v*)(bbase + ((nrow * 128 + ks * 64 + kgrp * 16) ^ ((nrow & 7) << 4)));
        }
        #pragma unroll
        for (int m = 0; m < 2; ++m)
          #pragma unroll
          for (int n = 0; n < 2; ++n)
            acc[m][n] = __builtin_amdgcn_mfma_f32_16x16x32_f16(af[m], bf[n], acc[m][n], 0, 0, 0);
      }
    }
    __syncthreads();
    tv0 = ntv0; tv1 = ntv1;
  }

  // ---- combine K-split halves, bias+relu, h -> f16 LDS ----
  if (kg == 1) {
    #pragma unroll
    for (int m = 0; m < 2; ++m)
      #pragma unroll
      for (int n = 0; n < 2; ++n)
        #pragma unroll
        for (int e = 0; e < 4; ++e) {
          int boxl = m * 16 + kgrp * 4 + e;
          int cnl = n * 16 + l15;
          *(float*)(lds + wc * 4096 + (boxl * 32 + cnl) * 4) = acc[m][n][e];
        }
  }
  __syncthreads();
  if (kg == 0) {
    float b1v[2];
    #pragma unroll
    for (int n = 0; n < 2; ++n) b1v[n] = b1h[wc * 32 + n * 16 + l15];
    #pragma unroll
    for (int m = 0; m < 2; ++m)
      #pragma unroll
      for (int n = 0; n < 2; ++n)
        #pragma unroll
        for (int e = 0; e < 4; ++e) {
          int boxl = m * 16 + kgrp * 4 + e;
          int cnl = n * 16 + l15;
          float hs = acc[m][n][e] + *(float*)(lds + wc * 4096 + (boxl * 32 + cnl) * 4) + b1v[n];
          unsigned short hb = f2hbits(fmaxf(hs, 0.0f));
          int cn = wc * 32 + cnl;
          int hby = 16384 + ((boxl * 256 + cn * 2) ^ ((boxl & 15) << 4));
          *(unsigned short*)(lds + hby) = hb;
        }
  } else if (head == 0) {
    int t2 = tid & 255;
    #pragma unroll
    for (int j = 0; j < 2; ++j) {
      int idx = t2 * 2 + j;
      out[(boxbase + (idx >> 4)) * 64 + 48 + (idx & 15)] = gvec[idx & 15];
    }
  }
  __syncthreads();

  // ---- layer 2: waves 0..3 each compute one 16x16 output quadrant ----
  if (kg == 0) {
    int m = wc & 1, n2 = wc >> 1;
    f4v a2 = (f4v){0.f, 0.f, 0.f, 0.f};
    int hrow = m * 16 + l15;
    int drow = n2 * 16 + l15;
    #pragma unroll
    for (int ks = 0; ks < 4; ++ks) {
      h8v ha = *(const h8v*)(lds + 16384 + ((hrow * 256 + ks * 64 + kgrp * 16) ^ ((hrow & 15) << 4)));
      h8v wb = *(const h8v*)(w2t + head * 8192 + drow * 256 + ks * 64 + kgrp * 16);
      a2 = __builtin_amdgcn_mfma_f32_16x16x32_f16(ha, wb, a2, 0, 0, 0);
    }
    int d = drow;
    if (d < odh) {
      float sc = scale_w[head];
      float b2v = b2h[d];
      #pragma unroll
      for (int e = 0; e < 4; ++e) {
        int box = boxbase + m * 16 + kgrp * 4 + e;
        out[box * 64 + colbase + d] = fmaxf(a2[e] + b2v, 0.0f) * sc;
      }
    }
  }
}

extern "C" void kernel_launch(void* const* d_in, const int* in_sizes, int n_in,
                              void* d_out, int out_size, void* d_ws, size_t ws_size,
                              hipStream_t stream) {
  const float* fm      = (const float*)d_in[0];
  const float* boxes   = (const float*)d_in[1];
  const float* W1a     = (const float*)d_in[2];
  const float* b1a     = (const float*)d_in[3];
  const float* W2a     = (const float*)d_in[4];
  const float* b2a     = (const float*)d_in[5];
  const float* W1b     = (const float*)d_in[6];
  const float* b1b     = (const float*)d_in[7];
  const float* W2b     = (const float*)d_in[8];
  const float* b2b     = (const float*)d_in[9];
  const float* W1c     = (const float*)d_in[10];
  const float* b1c     = (const float*)d_in[11];
  const float* W2c     = (const float*)d_in[12];
  const float* b2c     = (const float*)d_in[13];
  const float* scale_w = (const float*)d_in[14];
  const float* Wg      = (const float*)d_in[15];
  const float* bg      = (const float*)d_in[16];

  char* ws = (char*)d_ws;
  unsigned int* fmT32   = (unsigned int*)(ws + FMT_OFF);
  float* gf             = (float*)(ws + GF_OFF);
  float* g              = (float*)(ws + G_OFF);
  unsigned short* w1p   = (unsigned short*)(ws + W1P_OFF);
  unsigned short* w2t   = (unsigned short*)(ws + W2T_OFF);
  int2* wtab            = (int2*)(ws + WTAB_OFF);
  float* out            = (float*)d_out;

  k_mean<<<64, 256, 0, stream>>>(fm, gf);
  k_g<<<1, 64, 0, stream>>>(gf, Wg, bg, g);
  k_transpose<<<225, 256, 0, stream>>>(fm, fmT32);
  k_w1perm<<<384, 256, 0, stream>>>(W1a, W1b, W1c, w1p);
  k_w2prep<<<48, 256, 0, stream>>>(W2a, W2b, W2c, w2t);
  k_wtab<<<5728, 256, 0, stream>>>(boxes, wtab);
  k_main<<<768, 512, 0, stream>>>((const char*)ws + FMT_OFF, wtab,
                                  (const char*)ws + W1P_OFF, (const char*)ws + W2T_OFF, g,
                                  b1a, b1b, b1c, b2a, b2b, b2c, scale_w, out);
}

// Round 3
// 180.883 us; speedup vs baseline: 1.3936x; 1.2668x over previous
//
#include <hip/hip_runtime.h>
#include <hip/hip_fp16.h>
#include <stdint.h>

typedef float f4v __attribute__((ext_vector_type(4)));
typedef _Float16 h8v __attribute__((ext_vector_type(8)));

// ---- workspace byte offsets ----
#define FMT_OFF   0          // f16 fmT [14400][64]                : 1,843,200 B
#define GF_OFF    1843200    // f32 gf[64] channel sums (pre-div)
#define W1P_OFF   1843712    // f16 permuted+swizzled W1 (a,b,c)   : 2,932,736 B
#define W2T_OFF   4776448    // f16 w2t [3][32][128] linear        : 24,576 B
#define PBUF_OFF  4801024    // f16 partials 896 x [64][128]       : 14,680,064 B
// total: 19,481,088 B

#define GLD(gp, lp) __builtin_amdgcn_global_load_lds( \
    (const __attribute__((address_space(1))) uint32_t*)(uintptr_t)(gp), \
    (__attribute__((address_space(3))) uint32_t*)(uintptr_t)(lp), 16, 0, 0)

__device__ __forceinline__ unsigned short f2hbits(float f) {
  __half h = __float2half_rn(f);
  union { __half h; unsigned short s; } u; u.h = h; return u.s;
}
__device__ __forceinline__ __half2 uh(unsigned int x) {
  union { unsigned int u; __half2 h; } v; v.u = x; return v.h;
}
__device__ __forceinline__ unsigned int hu(__half2 h) {
  union { __half2 h; unsigned int u; } v; v.h = h; return v.u;
}

// ---- fm [64][120][120] f32 -> fmT [pix][64] f16 (LDS-tiled) + channel sums ----
__global__ void k_transpose(const float* __restrict__ fm, unsigned int* __restrict__ fmT32,
                            float* __restrict__ gf) {
  __shared__ float tile[64][65];
  int pixbase = blockIdx.x * 64, t = threadIdx.x;
  #pragma unroll
  for (int k = 0; k < 16; ++k) {
    int c = k * 4 + (t >> 6);
    tile[c][t & 63] = fm[c * 14400 + pixbase + (t & 63)];
  }
  __syncthreads();
  #pragma unroll
  for (int k = 0; k < 8; ++k) {
    int p = k * 8 + (t >> 5), i = t & 31;
    __half2 h = __floats2half2_rn(tile[2 * i][p], tile[2 * i + 1][p]);
    fmT32[(pixbase + p) * 32 + i] = hu(h);
  }
  // channel partial sums for global-feature path
  int ch = t >> 2, seg = t & 3;
  float s = 0.f;
  #pragma unroll
  for (int j = 0; j < 16; ++j) s += tile[ch][seg * 16 + j];
  s += __shfl_xor(s, 1);
  s += __shfl_xor(s, 2);
  if (seg == 0) atomicAdd(&gf[ch], s);
}

// ---- W1 -> per-point 16KB swizzled f16 chunks; blocks 384..386 do W2 prep ----
__global__ void k_w1w2(const float* __restrict__ W1a, const float* __restrict__ W1b,
                       const float* __restrict__ W1c,
                       const float* __restrict__ W2a, const float* __restrict__ W2b,
                       const float* __restrict__ W2c,
                       unsigned short* __restrict__ w1p, unsigned short* __restrict__ w2t) {
  __shared__ float row[7744];
  int bi = blockIdx.x, t = threadIdx.x;
  if (bi >= 384) {
    int head = bi - 384;
    const float* W2 = head == 0 ? W2a : (head == 1 ? W2b : W2c);
    int od = head == 0 ? 22 : 21;
    #pragma unroll
    for (int it = 0; it < 16; ++it) {
      int e = it * 256 + t;             // 4096 per head
      int n = e >> 7, k = e & 127;
      float v = (n < od) ? W2[n * 128 + k] : 0.0f;
      w2t[head * 4096 + e] = f2hbits(v);
    }
    return;
  }
  int head = bi >> 7, j = bi & 127;
  const float* W1; int rr, base;
  if (head == 0)      { W1 = W1a; rr = 9;   base = 0; }
  else if (head == 1) { W1 = W1b; rr = 49;  base = 147456; }
  else                { W1 = W1c; rr = 121; base = 950272; }
  int fin = rr * 64;
  for (int idx = t; idx < fin; idx += 256) row[idx] = W1[j * fin + idx];
  __syncthreads();
  int swz = (j & 7) << 4;
  for (int idx = t; idx < fin; idx += 256) {
    int c = idx & 63, p = idx >> 6;
    int byteoff = base + p * 16384 + ((j * 128 + c * 2) ^ swz);
    w1p[byteoff >> 1] = f2hbits(row[c * rr + p]);
  }
}

// ---- bilinear entry: {corner byte-offset, half2(wx,wy)} ----
__device__ __forceinline__ int2 mk_entry(float tx, float ty,
                                         float DX, float BX, float DY, float BY) {
  float ix = tx * DX + BX;
  float iy = ty * DY + BY;
  int x0 = min(max((int)floorf(ix), 0), 118);
  int y0 = min(max((int)floorf(iy), 0), 118);
  float wx = ix - (float)x0;
  float wy = iy - (float)y0;
  return make_int2((y0 * 120 + x0) * 128, (int)hu(__floats2half2_rn(wx, wy)));
}

// ---- bilinear sample of 4 channels -> swizzled LDS A write ----
__device__ __forceinline__ void sampleA(const char* __restrict__ fmT, int2 tv,
                                        int sbox, int scg, char* lds, int q) {
  __half2 wh = uh((unsigned int)tv.y);
  __half2 wx2 = __half2half2(__low2half(wh));
  __half2 wy2 = __half2half2(__high2half(wh));
  const char* src = fmT + tv.x + scg * 8;
  uint2 r00 = *(const uint2*)(src);
  uint2 r01 = *(const uint2*)(src + 128);
  uint2 r10 = *(const uint2*)(src + 15360);
  uint2 r11 = *(const uint2*)(src + 15488);
  __half2 a0 = uh(r00.x), a1 = uh(r00.y);
  __half2 b0 = uh(r01.x), b1 = uh(r01.y);
  __half2 c0 = uh(r10.x), c1 = uh(r10.y);
  __half2 d0 = uh(r11.x), d1 = uh(r11.y);
  __half2 t0 = __hfma2(wx2, __hsub2(b0, a0), a0);
  __half2 u0 = __hfma2(wx2, __hsub2(d0, c0), c0);
  __half2 v0 = __hfma2(wy2, __hsub2(u0, t0), t0);
  __half2 t1 = __hfma2(wx2, __hsub2(b1, a1), a1);
  __half2 u1 = __hfma2(wx2, __hsub2(d1, c1), c1);
  __half2 v1 = __hfma2(wy2, __hsub2(u1, t1), t1);
  int ab = q * 8192 + ((sbox * 128 + scg * 8) ^ ((sbox & 7) << 4));
  *(uint2*)(lds + ab) = make_uint2(hu(v0), hu(v1));
}

// ---- split-K partial GEMM: 64-box tile x 128 hidden, f16 partials ----
// LDS: A [0,16K) q*8K ; B [16K,48K) 16K+q*16K ; ebuf [48K+1K*2) at 49152
__global__ __launch_bounds__(512, 6) void k_main2(
    const char* __restrict__ fmT,
    const float* __restrict__ boxes,
    const char* __restrict__ w1p,
    unsigned short* __restrict__ pbuf)
{
  __shared__ __align__(16) char lds[51200];
  int bi = blockIdx.x;
  int head, tile64, split;
  if (bi < 512)      { head = 2; tile64 = bi >> 2;         split = bi & 3; }
  else if (bi < 768) { head = 1; tile64 = (bi - 512) >> 1; split = (bi - 512) & 1; }
  else               { head = 0; tile64 = bi - 768;        split = 0; }

  int psta, pcnt, w1base, pidx, R, rm; float invd;
  if (head == 2) {
    psta = split ? 31 + 30 * (split - 1) : 0; pcnt = split ? 30 : 31;
    w1base = 950272; pidx = tile64 * 4 + split; R = 11; rm = 5958; invd = 0.1f;
  } else if (head == 1) {
    psta = split * 25; pcnt = split ? 24 : 25;
    w1base = 147456; pidx = 512 + tile64 * 2 + split; R = 7; rm = 9363; invd = 0.166666667f;
  } else {
    psta = 0; pcnt = 9; w1base = 0; pidx = 768 + tile64; R = 3; rm = 21846; invd = 0.5f;
  }

  int tid = threadIdx.x;
  int w = tid >> 6, lane = tid & 63;
  int l15 = lane & 15, kgrp = lane >> 4;
  int kg = w >> 2, wc = w & 3;
  int boxbase = tile64 * 64;

  // entry-compute state (threads 0..127: eq = point parity, ebox = box in tile)
  int eq = tid >> 6, ebox = tid & 63;
  float DX = 0.f, BX = 0.f, DY = 0.f, BY = 0.f;
  int px = 0, py = 0;
  if (tid < 128) {
    float4 bx = ((const float4*)boxes)[boxbase + ebox];
    const float sc2 = 119.0f / 960.0f;
    DX = (bx.z - bx.x) * sc2; BX = bx.x * sc2;
    DY = (bx.w - bx.y) * sc2; BY = bx.y * sc2;
    int p0 = psta + eq;
    py = (p0 * rm) >> 16;
    px = p0 - py * R;
    *(int2*)(lds + 49152 + (eq * 64 + ebox) * 8) =
        mk_entry((float)px * invd, (float)py * invd, DX, BX, DY, BY);
  }

  f4v acc[4][2];
  #pragma unroll
  for (int m = 0; m < 4; ++m)
    #pragma unroll
    for (int n = 0; n < 2; ++n) acc[m][n] = (f4v){0.f, 0.f, 0.f, 0.f};

  const char* w1g = w1p + w1base;
  int niter = (pcnt + 1) >> 1;
  __syncthreads();

  for (int it = 0; it < niter; ++it) {
    int p0 = psta + 2 * it;
    bool has1 = (2 * it + 1) < pcnt;
    int cur = it & 1, nxt = cur ^ 1;

    // stage B chunks (pre-swizzled in global -> linear LDS)
    {
      const char* s0 = w1g + p0 * 16384 + w * 2048 + lane * 16;
      char* d0 = lds + 16384 + w * 2048;
      GLD(s0, d0); GLD(s0 + 1024, d0 + 1024);
      if (has1) {
        GLD(s0 + 16384, d0 + 16384); GLD(s0 + 17408, d0 + 17408);
      }
    }

    // compute next iteration's entries
    if (tid < 128) {
      px += 2; if (px >= R) { px -= R; ++py; }
      *(int2*)(lds + 49152 + nxt * 1024 + (eq * 64 + ebox) * 8) =
          mk_entry((float)px * invd, (float)py * invd, DX, BX, DY, BY);
    }

    // sample A tiles (2 units per thread per point)
    {
      const char* eb = lds + 49152 + cur * 1024;
      int sb0 = tid >> 4, scg = tid & 15;
      #pragma unroll
      for (int u = 0; u < 4; ++u) {
        int rep = u & 1, q = u >> 1;
        if (q == 0 || has1) {
          int sbox = rep * 32 + sb0;
          int2 tv = *(const int2*)(eb + (q * 64 + sbox) * 8);
          sampleA(fmT, tv, sbox, scg, lds, q);
        }
      }
    }
    __syncthreads();

    if (kg == 0 || has1) {
      const char* abase = lds + kg * 8192;
      const char* bbase = lds + 16384 + kg * 16384;
      #pragma unroll
      for (int ks = 0; ks < 2; ++ks) {
        h8v bf[2];
        #pragma unroll
        for (int n = 0; n < 2; ++n) {
          int nrow = wc * 32 + n * 16 + l15;
          bf[n] = *(const h8v*)(bbase + ((nrow * 128 + ks * 64 + kgrp * 16) ^ ((nrow & 7) << 4)));
        }
        #pragma unroll
        for (int m = 0; m < 4; ++m) {
          int rrow = m * 16 + l15;
          h8v af = *(const h8v*)(abase + ((rrow * 128 + ks * 64 + kgrp * 16) ^ ((rrow & 7) << 4)));
          #pragma unroll
          for (int n = 0; n < 2; ++n)
            acc[m][n] = __builtin_amdgcn_mfma_f32_16x16x32_f16(af, bf[n], acc[m][n], 0, 0, 0);
        }
      }
    }
    __syncthreads();
  }

  // combine kg halves -> f16 partial to global
  if (kg == 1) {
    #pragma unroll
    for (int m = 0; m < 4; ++m)
      #pragma unroll
      for (int n = 0; n < 2; ++n)
        #pragma unroll
        for (int e = 0; e < 4; ++e) {
          int boxl = m * 16 + kgrp * 4 + e;
          int cnl = wc * 32 + n * 16 + l15;
          *(float*)(lds + (boxl * 128 + cnl) * 4) = acc[m][n][e];
        }
  }
  __syncthreads();
  if (kg == 0) {
    unsigned short* pdst = pbuf + pidx * 8192;
    #pragma unroll
    for (int m = 0; m < 4; ++m)
      #pragma unroll
      for (int n = 0; n < 2; ++n)
        #pragma unroll
        for (int e = 0; e < 4; ++e) {
          int boxl = m * 16 + kgrp * 4 + e;
          int cnl = wc * 32 + n * 16 + l15;
          float v = acc[m][n][e] + *(const float*)(lds + (boxl * 128 + cnl) * 4);
          pdst[boxl * 128 + cnl] = f2hbits(v);
        }
  }
}

// ---- combine partials, bias+relu, layer-2 MFMA, write out (+g cols) ----
__global__ __launch_bounds__(256) void k_combine(
    const unsigned short* __restrict__ pbuf,
    const unsigned short* __restrict__ w2t,
    const float* __restrict__ gf,
    const float* __restrict__ Wg, const float* __restrict__ bg,
    const float* __restrict__ b1a, const float* __restrict__ b1b, const float* __restrict__ b1c,
    const float* __restrict__ b2a, const float* __restrict__ b2b, const float* __restrict__ b2c,
    const float* __restrict__ scale_w,
    float* __restrict__ out)
{
  __shared__ __align__(16) char lds[8192 + 256];
  float* gv = (float*)(lds + 8192);
  int b = blockIdx.x, tid = threadIdx.x;
  int tile64 = b >> 1, rowoff = (b & 1) * 32;
  int boxbase = b * 32;
  int w = tid >> 6, lane = tid & 63, l15 = lane & 15, kgrp = lane >> 4;

  if (tid < 16) {
    float s = bg[tid];
    for (int c = 0; c < 64; ++c) s += gf[c] * (1.0f / 14400.0f) * Wg[tid * 64 + c];
    gv[tid] = s;
  }

  int row = tid >> 3, col0 = (tid & 7) * 16;
  const float* b1s[3] = {b1a, b1b, b1c};
  const float* b2s[3] = {b2a, b2b, b2c};

  #pragma unroll
  for (int h = 0; h < 3; ++h) {
    int S, pb, colbase, odh;
    if (h == 0)      { S = 1; pb = 768 + tile64;     colbase = 0;  odh = 22; }
    else if (h == 1) { S = 2; pb = 512 + tile64 * 2; colbase = 22; odh = 21; }
    else             { S = 4; pb = tile64 * 4;       colbase = 43; odh = 5; }

    float f[16];
    #pragma unroll
    for (int j = 0; j < 16; ++j) f[j] = 0.f;
    #pragma unroll
    for (int s = 0; s < 4; ++s) {
      if (s < S) {
        const unsigned short* src = pbuf + (pb + s) * 8192 + (rowoff + row) * 128 + col0;
        uint4 v0 = *(const uint4*)(src);
        uint4 v1 = *(const uint4*)(src + 8);
        unsigned int uu[8] = {v0.x, v0.y, v0.z, v0.w, v1.x, v1.y, v1.z, v1.w};
        #pragma unroll
        for (int k = 0; k < 8; ++k) {
          __half2 hv = uh(uu[k]);
          f[k * 2]     += __low2float(hv);
          f[k * 2 + 1] += __high2float(hv);
        }
      }
    }
    unsigned int pk[8];
    #pragma unroll
    for (int k = 0; k < 8; ++k) {
      float a  = fmaxf(f[2 * k]     + b1s[h][col0 + 2 * k],     0.f);
      float c2 = fmaxf(f[2 * k + 1] + b1s[h][col0 + 2 * k + 1], 0.f);
      pk[k] = hu(__floats2half2_rn(a, c2));
    }
    int swz = (row & 15) << 4;
    int a0 = (row * 256 + col0 * 2) ^ swz;
    int a1 = (row * 256 + col0 * 2 + 16) ^ swz;
    *(uint4*)(lds + a0) = make_uint4(pk[0], pk[1], pk[2], pk[3]);
    *(uint4*)(lds + a1) = make_uint4(pk[4], pk[5], pk[6], pk[7]);
    __syncthreads();

    {
      int m = w & 1, n2 = w >> 1;
      f4v a2 = (f4v){0.f, 0.f, 0.f, 0.f};
      int hrow = m * 16 + l15, drow = n2 * 16 + l15;
      #pragma unroll
      for (int ks = 0; ks < 4; ++ks) {
        h8v ha = *(const h8v*)(lds + ((hrow * 256 + ks * 64 + kgrp * 16) ^ ((hrow & 15) << 4)));
        h8v wb = *(const h8v*)((const char*)w2t + h * 8192 + drow * 256 + ks * 64 + kgrp * 16);
        a2 = __builtin_amdgcn_mfma_f32_16x16x32_f16(ha, wb, a2, 0, 0, 0);
      }
      if (drow < odh) {
        float scv = scale_w[h];
        float b2v = b2s[h][drow];
        #pragma unroll
        for (int e = 0; e < 4; ++e) {
          int box = boxbase + m * 16 + kgrp * 4 + e;
          out[box * 64 + colbase + drow] = fmaxf(a2[e] + b2v, 0.f) * scv;
        }
      }
    }
    __syncthreads();
  }

  // g columns 48..63
  {
    int i0 = tid * 2;
    #pragma unroll
    for (int j2 = 0; j2 < 2; ++j2) {
      int idx = i0 + j2;
      out[(boxbase + (idx >> 4)) * 64 + 48 + (idx & 15)] = gv[idx & 15];
    }
  }
}

extern "C" void kernel_launch(void* const* d_in, const int* in_sizes, int n_in,
                              void* d_out, int out_size, void* d_ws, size_t ws_size,
                              hipStream_t stream) {
  const float* fm      = (const float*)d_in[0];
  const float* boxes   = (const float*)d_in[1];
  const float* W1a     = (const float*)d_in[2];
  const float* b1a     = (const float*)d_in[3];
  const float* W2a     = (const float*)d_in[4];
  const float* b2a     = (const float*)d_in[5];
  const float* W1b     = (const float*)d_in[6];
  const float* b1b     = (const float*)d_in[7];
  const float* W2b     = (const float*)d_in[8];
  const float* b2b     = (const float*)d_in[9];
  const float* W1c     = (const float*)d_in[10];
  const float* b1c     = (const float*)d_in[11];
  const float* W2c     = (const float*)d_in[12];
  const float* b2c     = (const float*)d_in[13];
  const float* scale_w = (const float*)d_in[14];
  const float* Wg      = (const float*)d_in[15];
  const float* bg      = (const float*)d_in[16];

  char* ws = (char*)d_ws;
  unsigned int* fmT32 = (unsigned int*)(ws + FMT_OFF);
  float* gf           = (float*)(ws + GF_OFF);
  unsigned short* w1p = (unsigned short*)(ws + W1P_OFF);
  unsigned short* w2t = (unsigned short*)(ws + W2T_OFF);
  unsigned short* pbuf= (unsigned short*)(ws + PBUF_OFF);
  float* out          = (float*)d_out;

  hipMemsetAsync(gf, 0, 256, stream);
  k_transpose<<<225, 256, 0, stream>>>(fm, fmT32, gf);
  k_w1w2<<<387, 256, 0, stream>>>(W1a, W1b, W1c, W2a, W2b, W2c, w1p, w2t);
  k_main2<<<896, 512, 0, stream>>>((const char*)ws + FMT_OFF, boxes,
                                   (const char*)ws + W1P_OFF, pbuf);
  k_combine<<<256, 256, 0, stream>>>(pbuf, w2t, gf, Wg, bg,
                                     b1a, b1b, b1c, b2a, b2b, b2c, scale_w, out);
}

// Round 7
// 166.992 us; speedup vs baseline: 1.5096x; 1.0832x over previous
//
#include <hip/hip_runtime.h>
#include <hip/hip_fp16.h>
#include <stdint.h>

typedef float f4v __attribute__((ext_vector_type(4)));
typedef _Float16 h8v __attribute__((ext_vector_type(8)));

// ---- workspace byte offsets ----
#define FMT_OFF   0          // f16 fmT [14400][64]                : 1,843,200 B
#define GF_OFF    1843200    // f32 gf[64] channel sums (pre-div)
#define W1P_OFF   1843712    // f16 permuted+swizzled W1 (a,b,c)   : 2,932,736 B
#define W2T_OFF   4776448    // f16 w2t [3][32][128] linear        : 24,576 B
#define PBUF_OFF  4801024    // f16 partials 448 x [128][128]      : 14,680,064 B

#define GLD(gp, lp) __builtin_amdgcn_global_load_lds( \
    (const __attribute__((address_space(1))) uint32_t*)(uintptr_t)(gp), \
    (__attribute__((address_space(3))) uint32_t*)(uintptr_t)(lp), 16, 0, 0)

__device__ __forceinline__ unsigned short f2hbits(float f) {
  __half h = __float2half_rn(f);
  union { __half h; unsigned short s; } u; u.h = h; return u.s;
}
__device__ __forceinline__ __half2 uh(unsigned int x) {
  union { unsigned int u; __half2 h; } v; v.u = x; return v.h;
}
__device__ __forceinline__ unsigned int hu(__half2 h) {
  union { __half2 h; unsigned int u; } v; v.h = h; return v.u;
}

// ---- fm [64][120][120] f32 -> fmT [pix][64] f16 (LDS-tiled) + channel sums ----
__global__ void k_transpose(const float* __restrict__ fm, unsigned int* __restrict__ fmT32,
                            float* __restrict__ gf) {
  __shared__ float tile[64][65];
  int pixbase = blockIdx.x * 64, t = threadIdx.x;
  #pragma unroll
  for (int k = 0; k < 16; ++k) {
    int c = k * 4 + (t >> 6);
    tile[c][t & 63] = fm[c * 14400 + pixbase + (t & 63)];
  }
  __syncthreads();
  #pragma unroll
  for (int k = 0; k < 8; ++k) {
    int p = k * 8 + (t >> 5), i = t & 31;
    __half2 h = __floats2half2_rn(tile[2 * i][p], tile[2 * i + 1][p]);
    fmT32[(pixbase + p) * 32 + i] = hu(h);
  }
  int ch = t >> 2, seg = t & 3;
  float s = 0.f;
  #pragma unroll
  for (int j = 0; j < 16; ++j) s += tile[ch][seg * 16 + j];
  s += __shfl_xor(s, 1);
  s += __shfl_xor(s, 2);
  if (seg == 0) atomicAdd(&gf[ch], s);
}

// ---- W1 -> per-point 16KB swizzled f16 chunks; blocks 384..386 do W2 prep ----
__global__ void k_w1w2(const float* __restrict__ W1a, const float* __restrict__ W1b,
                       const float* __restrict__ W1c,
                       const float* __restrict__ W2a, const float* __restrict__ W2b,
                       const float* __restrict__ W2c,
                       unsigned short* __restrict__ w1p, unsigned short* __restrict__ w2t) {
  __shared__ float row[7744];
  int bi = blockIdx.x, t = threadIdx.x;
  if (bi >= 384) {
    int head = bi - 384;
    const float* W2 = head == 0 ? W2a : (head == 1 ? W2b : W2c);
    int od = head == 0 ? 22 : 21;
    #pragma unroll
    for (int it = 0; it < 16; ++it) {
      int e = it * 256 + t;
      int n = e >> 7, k = e & 127;
      float v = (n < od) ? W2[n * 128 + k] : 0.0f;
      w2t[head * 4096 + e] = f2hbits(v);
    }
    return;
  }
  int head = bi >> 7, j = bi & 127;
  const float* W1; int rr, base;
  if (head == 0)      { W1 = W1a; rr = 9;   base = 0; }
  else if (head == 1) { W1 = W1b; rr = 49;  base = 147456; }
  else                { W1 = W1c; rr = 121; base = 950272; }
  int fin = rr * 64;
  for (int idx = t; idx < fin; idx += 256) row[idx] = W1[j * fin + idx];
  __syncthreads();
  int swz = (j & 7) << 4;
  for (int idx = t; idx < fin; idx += 256) {
    int c = idx & 63, p = idx >> 6;
    int byteoff = base + p * 16384 + ((j * 128 + c * 2) ^ swz);
    w1p[byteoff >> 1] = f2hbits(row[c * rr + p]);
  }
}

// ---- bilinear entry: {corner byte-offset, half2(wx,wy)} ----
__device__ __forceinline__ int2 mk_entry(float tx, float ty,
                                         float DX, float BX, float DY, float BY) {
  float ix = tx * DX + BX;
  float iy = ty * DY + BY;
  int x0 = min(max((int)floorf(ix), 0), 118);
  int y0 = min(max((int)floorf(iy), 0), 118);
  float wx = ix - (float)x0;
  float wy = iy - (float)y0;
  return make_int2((y0 * 120 + x0) * 128, (int)hu(__floats2half2_rn(wx, wy)));
}

__device__ __forceinline__ unsigned lerp1(unsigned aa, unsigned bb, unsigned cc, unsigned dd,
                                          __half2 wx2, __half2 wy2) {
  __half2 a = uh(aa), b = uh(bb), c = uh(cc), d = uh(dd);
  __half2 t = __hfma2(wx2, __hsub2(b, a), a);
  __half2 u2 = __hfma2(wx2, __hsub2(d, c), c);
  return hu(__hfma2(wy2, __hsub2(u2, t), t));
}

// issue sample loads for one point: 2 units (boxes sg, sg+64) x 4 corners x 16B
__device__ __forceinline__ void issue_pt(const char* lds, int ebOff, const char* __restrict__ fmT,
                                         int sg, int scg8, uint4 cs[2][4],
                                         __half2* wx2v, __half2* wy2v) {
  #pragma unroll
  for (int u = 0; u < 2; ++u) {
    int2 e = *(const int2*)(lds + ebOff + (sg + u * 64) * 8);
    __half2 wh = uh((unsigned)e.y);
    wx2v[u] = __half2half2(__low2half(wh));
    wy2v[u] = __half2half2(__high2half(wh));
    const char* src = fmT + e.x + scg8 * 16;
    cs[u][0] = *(const uint4*)(src);
    cs[u][1] = *(const uint4*)(src + 128);
    cs[u][2] = *(const uint4*)(src + 15360);
    cs[u][3] = *(const uint4*)(src + 15488);
  }
}

// ---- fused ROI-sample + layer-1 GEMM, 128-box tiles, T14 pipeline ----
// LDS: A [0,16K) ; B[2] [16K,48K) ; ebuf[2] [48K, 48K+2K)
__global__ __launch_bounds__(512, 4) void k_main3(
    const char* __restrict__ fmT,
    const float* __restrict__ boxes,
    const char* __restrict__ w1p,
    unsigned short* __restrict__ pbuf)
{
  __shared__ __align__(16) char lds[51200];
  int bi = blockIdx.x;
  int head, tile, split;
  if (bi < 256)      { head = 2; tile = bi >> 2;         split = bi & 3; }
  else if (bi < 384) { head = 1; tile = (bi - 256) >> 1; split = (bi - 256) & 1; }
  else               { head = 0; tile = bi - 384;        split = 0; }

  int psta, pcnt, w1base, R, rm; float invd;
  if (head == 2)      { psta = split ? 31 + 30 * (split - 1) : 0; pcnt = split ? 30 : 31;
                        w1base = 950272; R = 11; rm = 5958;  invd = 0.1f; }
  else if (head == 1) { psta = split * 25; pcnt = 25 - split;
                        w1base = 147456; R = 7;  rm = 9363;  invd = 0.166666667f; }
  else                { psta = 0; pcnt = 9; w1base = 0; R = 3; rm = 21846; invd = 0.5f; }

  int tid = threadIdx.x;
  int w = tid >> 6, lane = tid & 63;
  int l15 = lane & 15, kgrp = lane >> 4;
  int wm = w & 1, wc = w >> 1;          // wave tile: 64 boxes x 32 cols
  int sg = tid >> 3, scg8 = tid & 7;    // sampler: boxes sg, sg+64; 8-ch group
  int boxbase = tile * 128;

  // box params for entry compute (tid<128 owns box=tid)
  float DX = 0.f, BX = 0.f, DY = 0.f, BY = 0.f;
  if (tid < 128) {
    float4 bx = ((const float4*)boxes)[boxbase + tid];
    const float sc2 = 119.0f / 960.0f;
    DX = (bx.z - bx.x) * sc2; BX = bx.x * sc2;
    DY = (bx.w - bx.y) * sc2; BY = bx.y * sc2;
  }

  f4v acc[4][2];
  #pragma unroll
  for (int m = 0; m < 4; ++m)
    #pragma unroll
    for (int n = 0; n < 2; ++n) acc[m][n] = (f4v){0.f, 0.f, 0.f, 0.f};

  const char* w1g = w1p + w1base;
  uint4 cs[2][4];
  __half2 wx2v[2], wy2v[2];

  // ---- prologue: entries(0)->ebuf[0], entries(1)->ebuf[1]; GLD B[0] ----
  if (tid < 128) {
    #pragma unroll
    for (int q = 0; q < 2; ++q) {
      int p = psta + q;
      int py = (p * rm) >> 16, px = p - py * R;
      *(int2*)(lds + 49152 + q * 1024 + tid * 8) =
          mk_entry((float)px * invd, (float)py * invd, DX, BX, DY, BY);
    }
  }
  {
    const char* s0 = w1g + psta * 16384 + w * 2048 + lane * 16;
    char* d0 = lds + 16384 + w * 2048;
    GLD(s0, d0); GLD(s0 + 1024, d0 + 1024);
  }
  __syncthreads();
  issue_pt(lds, 49152, fmT, sg, scg8, cs, wx2v, wy2v);   // samples(0)

  for (int t = 0; t < pcnt; ++t) {
    int cur = t & 1, nxt = cur ^ 1;
    bool more = (t + 1) < pcnt;

    // ---- phase 1: lerp samples(t) -> A; compute entries(t+2) into regs ----
    #pragma unroll
    for (int u = 0; u < 2; ++u) {
      int sbox = sg + u * 64;
      uint4 r;
      r.x = lerp1(cs[u][0].x, cs[u][1].x, cs[u][2].x, cs[u][3].x, wx2v[u], wy2v[u]);
      r.y = lerp1(cs[u][0].y, cs[u][1].y, cs[u][2].y, cs[u][3].y, wx2v[u], wy2v[u]);
      r.z = lerp1(cs[u][0].z, cs[u][1].z, cs[u][2].z, cs[u][3].z, wx2v[u], wy2v[u]);
      r.w = lerp1(cs[u][0].w, cs[u][1].w, cs[u][2].w, cs[u][3].w, wx2v[u], wy2v[u]);
      *(uint4*)(lds + ((sbox * 128 + scg8 * 16) ^ ((sbox & 7) << 4))) = r;
    }
    int2 ne;
    if (tid < 128) {
      int p = psta + min(t + 2, pcnt - 1);
      int py = (p * rm) >> 16, px = p - py * R;
      ne = mk_entry((float)px * invd, (float)py * invd, DX, BX, DY, BY);
    }
    __syncthreads();   // barrier1: A visible (nothing in vmem queue here)

    // ---- phase 2: prefetch t+1 (GLD B[nxt] + sample loads), entries ds_write, MFMA(t) ----
    if (tid < 128) *(int2*)(lds + 49152 + cur * 1024 + tid * 8) = ne;
    if (more) {
      const char* s0 = w1g + (psta + t + 1) * 16384 + w * 2048 + lane * 16;
      char* d0 = lds + 16384 + nxt * 16384 + w * 2048;
      GLD(s0, d0); GLD(s0 + 1024, d0 + 1024);
      issue_pt(lds, 49152 + nxt * 1024, fmT, sg, scg8, cs, wx2v, wy2v);
    }
    {
      const char* bb = lds + 16384 + cur * 16384;
      #pragma unroll
      for (int ks = 0; ks < 2; ++ks) {
        int n0 = wc * 32 + l15, n1 = n0 + 16;
        h8v bf0 = *(const h8v*)(bb + ((n0 * 128 + ks * 64 + kgrp * 16) ^ ((n0 & 7) << 4)));
        h8v bf1 = *(const h8v*)(bb + ((n1 * 128 + ks * 64 + kgrp * 16) ^ ((n1 & 7) << 4)));
        #pragma unroll
        for (int m = 0; m < 4; ++m) {
          int rrow = wm * 64 + m * 16 + l15;
          h8v af = *(const h8v*)(lds + ((rrow * 128 + ks * 64 + kgrp * 16) ^ ((rrow & 7) << 4)));
          acc[m][0] = __builtin_amdgcn_mfma_f32_16x16x32_f16(af, bf0, acc[m][0], 0, 0, 0);
          acc[m][1] = __builtin_amdgcn_mfma_f32_16x16x32_f16(af, bf1, acc[m][1], 0, 0, 0);
        }
      }
    }
    __syncthreads();   // barrier2: drains prefetches that flew during MFMA
  }

  // ---- epilogue: f16 partial -> pbuf[bi] ----
  unsigned short* pdst = pbuf + (size_t)bi * 16384;
  #pragma unroll
  for (int m = 0; m < 4; ++m)
    #pragma unroll
    for (int n = 0; n < 2; ++n)
      #pragma unroll
      for (int e = 0; e < 4; ++e) {
        int boxl = wm * 64 + m * 16 + kgrp * 4 + e;
        int cnl = wc * 32 + n * 16 + l15;
        pdst[boxl * 128 + cnl] = f2hbits(acc[m][n][e]);
      }
}

// ---- combine partials, bias+relu, layer-2 MFMA, write out (+g cols) ----
__global__ __launch_bounds__(256) void k_combine(
    const unsigned short* __restrict__ pbuf,
    const unsigned short* __restrict__ w2t,
    const float* __restrict__ gf,
    const float* __restrict__ Wg, const float* __restrict__ bg,
    const float* __restrict__ b1a, const float* __restrict__ b1b, const float* __restrict__ b1c,
    const float* __restrict__ b2a, const float* __restrict__ b2b, const float* __restrict__ b2c,
    const float* __restrict__ scale_w,
    float* __restrict__ out)
{
  __shared__ __align__(16) char lds[8192 + 256];
  float* gv = (float*)(lds + 8192);
  int b = blockIdx.x, tid = threadIdx.x;
  int tile = b >> 2, rowoff = (b & 3) * 32;
  int boxbase = b * 32;
  int w = tid >> 6, lane = tid & 63, l15 = lane & 15, kgrp = lane >> 4;

  if (tid < 16) {
    float s = bg[tid];
    for (int c = 0; c < 64; ++c) s += gf[c] * (1.0f / 14400.0f) * Wg[tid * 64 + c];
    gv[tid] = s;
  }

  int row = tid >> 3, col0 = (tid & 7) * 16;
  const float* b1s[3] = {b1a, b1b, b1c};
  const float* b2s[3] = {b2a, b2b, b2c};

  #pragma unroll
  for (int h = 0; h < 3; ++h) {
    int S, pb, colbase, odh;
    if (h == 0)      { S = 1; pb = 384 + tile;     colbase = 0;  odh = 22; }
    else if (h == 1) { S = 2; pb = 256 + tile * 2; colbase = 22; odh = 21; }
    else             { S = 4; pb = tile * 4;       colbase = 43; odh = 5; }

    float f[16];
    #pragma unroll
    for (int j = 0; j < 16; ++j) f[j] = 0.f;
    #pragma unroll
    for (int s = 0; s < 4; ++s) {
      if (s < S) {
        const unsigned short* src = pbuf + (size_t)(pb + s) * 16384 + (rowoff + row) * 128 + col0;
        uint4 v0 = *(const uint4*)(src);
        uint4 v1 = *(const uint4*)(src + 8);
        unsigned int uu[8] = {v0.x, v0.y, v0.z, v0.w, v1.x, v1.y, v1.z, v1.w};
        #pragma unroll
        for (int k = 0; k < 8; ++k) {
          __half2 hv = uh(uu[k]);
          f[k * 2]     += __low2float(hv);
          f[k * 2 + 1] += __high2float(hv);
        }
      }
    }
    unsigned int pk[8];
    #pragma unroll
    for (int k = 0; k < 8; ++k) {
      float a  = fmaxf(f[2 * k]     + b1s[h][col0 + 2 * k],     0.f);
      float c2 = fmaxf(f[2 * k + 1] + b1s[h][col0 + 2 * k + 1], 0.f);
      pk[k] = hu(__floats2half2_rn(a, c2));
    }
    int swz = (row & 15) << 4;
    int a0 = (row * 256 + col0 * 2) ^ swz;
    int a1 = (row * 256 + col0 * 2 + 16) ^ swz;
    *(uint4*)(lds + a0) = make_uint4(pk[0], pk[1], pk[2], pk[3]);
    *(uint4*)(lds + a1) = make_uint4(pk[4], pk[5], pk[6], pk[7]);
    __syncthreads();

    {
      int m = w & 1, n2 = w >> 1;
      f4v a2 = (f4v){0.f, 0.f, 0.f, 0.f};
      int hrow = m * 16 + l15, drow = n2 * 16 + l15;
      #pragma unroll
      for (int ks = 0; ks < 4; ++ks) {
        h8v ha = *(const h8v*)(lds + ((hrow * 256 + ks * 64 + kgrp * 16) ^ ((hrow & 15) << 4)));
        h8v wb = *(const h8v*)((const char*)w2t + h * 8192 + drow * 256 + ks * 64 + kgrp * 16);
        a2 = __builtin_amdgcn_mfma_f32_16x16x32_f16(ha, wb, a2, 0, 0, 0);
      }
      if (drow < odh) {
        float scv = scale_w[h];
        float b2v = b2s[h][drow];
        #pragma unroll
        for (int e = 0; e < 4; ++e) {
          int box = boxbase + m * 16 + kgrp * 4 + e;
          out[box * 64 + colbase + drow] = fmaxf(a2[e] + b2v, 0.f) * scv;
        }
      }
    }
    __syncthreads();
  }

  {
    int i0 = tid * 2;
    #pragma unroll
    for (int j2 = 0; j2 < 2; ++j2) {
      int idx = i0 + j2;
      out[(boxbase + (idx >> 4)) * 64 + 48 + (idx & 15)] = gv[idx & 15];
    }
  }
}

extern "C" void kernel_launch(void* const* d_in, const int* in_sizes, int n_in,
                              void* d_out, int out_size, void* d_ws, size_t ws_size,
                              hipStream_t stream) {
  const float* fm      = (const float*)d_in[0];
  const float* boxes   = (const float*)d_in[1];
  const float* W1a     = (const float*)d_in[2];
  const float* b1a     = (const float*)d_in[3];
  const float* W2a     = (const float*)d_in[4];
  const float* b2a     = (const float*)d_in[5];
  const float* W1b     = (const float*)d_in[6];
  const float* b1b     = (const float*)d_in[7];
  const float* W2b     = (const float*)d_in[8];
  const float* b2b     = (const float*)d_in[9];
  const float* W1c     = (const float*)d_in[10];
  const float* b1c     = (const float*)d_in[11];
  const float* W2c     = (const float*)d_in[12];
  const float* b2c     = (const float*)d_in[13];
  const float* scale_w = (const float*)d_in[14];
  const float* Wg      = (const float*)d_in[15];
  const float* bg      = (const float*)d_in[16];

  char* ws = (char*)d_ws;
  unsigned int* fmT32 = (unsigned int*)(ws + FMT_OFF);
  float* gf           = (float*)(ws + GF_OFF);
  unsigned short* w1p = (unsigned short*)(ws + W1P_OFF);
  unsigned short* w2t = (unsigned short*)(ws + W2T_OFF);
  unsigned short* pbuf= (unsigned short*)(ws + PBUF_OFF);
  float* out          = (float*)d_out;

  hipMemsetAsync(gf, 0, 256, stream);
  k_transpose<<<225, 256, 0, stream>>>(fm, fmT32, gf);
  k_w1w2<<<387, 256, 0, stream>>>(W1a, W1b, W1c, W2a, W2b, W2c, w1p, w2t);
  k_main3<<<448, 512, 0, stream>>>((const char*)ws + FMT_OFF, boxes,
                                   (const char*)ws + W1P_OFF, pbuf);
  k_combine<<<256, 256, 0, stream>>>(pbuf, w2t, gf, Wg, bg,
                                     b1a, b1b, b1c, b2a, b2b, b2c, scale_w, out);
}